// Round 4
// baseline (142.240 us; speedup 1.0000x reference)
//
#include <hip/hip_runtime.h>

#define N_RAYS 262144
#define N_SAMPLES 128

typedef float vf2 __attribute__((ext_vector_type(2)));

// One wave (64 lanes) per ray; 2 consecutive samples per lane.
// All streaming loads/stores non-temporal; coalesced block epilogue.
__global__ __launch_bounds__(256) void volrend_kernel(
    const float* __restrict__ sigma,
    const float* __restrict__ colors,
    const float* __restrict__ z_vals,
    const float* __restrict__ rays_d,
    float* __restrict__ out)
{
    const int wid  = threadIdx.x >> 6;   // wave in block: 0..3
    const int lane = threadIdx.x & 63;
    const int ray  = blockIdx.x * 4 + wid;

    __shared__ float sred[4][6];         // per-ray: cr,cg,cb,depth,disp,acc

    // ---- issue ALL global loads up front (max MLP) ----
    const int s0 = lane * 2;
    const size_t rbase = (size_t)ray * N_SAMPLES;
    const vf2 zv = __builtin_nontemporal_load(
        reinterpret_cast<const vf2*>(z_vals + rbase + s0));
    const vf2 sg = __builtin_nontemporal_load(
        reinterpret_cast<const vf2*>(sigma + rbase + s0));
    const float* cbase = colors + rbase * 3 + (size_t)s0 * 3;
    const vf2 c01 = __builtin_nontemporal_load(
        reinterpret_cast<const vf2*>(cbase + 0));
    const vf2 c23 = __builtin_nontemporal_load(
        reinterpret_cast<const vf2*>(cbase + 2));
    const vf2 c45 = __builtin_nontemporal_load(
        reinterpret_cast<const vf2*>(cbase + 4));
    const float dx = rays_d[ray * 3 + 0];
    const float dy = rays_d[ray * 3 + 1];
    const float dz = rays_d[ray * 3 + 2];
    // sample s0   : color (c01.x, c01.y, c23.x)
    // sample s0+1 : color (c23.y, c45.x, c45.y)

    const float nrm = sqrtf(dx * dx + dy * dy + dz * dz);

    // ---- dists ----
    const float z_next = __shfl_down(zv.x, 1, 64);       // z[s0+2]
    const float dist0 = (zv.y - zv.x) * nrm;
    const float dist1 = (lane == 63) ? (1e10f * nrm) : (z_next - zv.y) * nrm;

    // ---- alpha / survival ----
    const float e0 = __expf(-fmaxf(sg.x, 0.0f) * dist0);
    const float e1 = __expf(-fmaxf(sg.y, 0.0f) * dist1);
    const float alpha0 = 1.0f - e0;
    const float alpha1 = 1.0f - e1;
    const float a0 = e0 + 1e-10f;   // (1 - alpha) + 1e-10
    const float a1 = e1 + 1e-10f;

    // ---- exclusive prefix product over 128 samples (2/lane) ----
    float scan = a0 * a1;
    #pragma unroll
    for (int off = 1; off < 64; off <<= 1) {
        const float n = __shfl_up(scan, off, 64);
        if (lane >= off) scan *= n;
    }
    float excl = __shfl_up(scan, 1, 64);
    if (lane == 0) excl = 1.0f;

    const float w0 = excl * alpha0;
    const float w1 = excl * a0 * alpha1;

    // ---- weights store (early, non-temporal, coalesced 512B/wave) ----
    const size_t R = N_RAYS;
    vf2 wv; wv.x = w0; wv.y = w1;
    __builtin_nontemporal_store(
        wv, reinterpret_cast<vf2*>(out + 3 * R + rbase + s0));

    // ---- reductions ----
    float acc   = w0 + w1;
    float depth = w0 * zv.x  + w1 * zv.y;
    float cr    = w0 * c01.x + w1 * c23.y;
    float cg    = w0 * c01.y + w1 * c45.x;
    float cb    = w0 * c23.x + w1 * c45.y;
    #pragma unroll
    for (int off = 32; off; off >>= 1) {
        acc   += __shfl_xor(acc,   off, 64);
        depth += __shfl_xor(depth, off, 64);
        cr    += __shfl_xor(cr,    off, 64);
        cg    += __shfl_xor(cg,    off, 64);
        cb    += __shfl_xor(cb,    off, 64);
    }

    if (lane == 0) {
        sred[wid][0] = cr;
        sred[wid][1] = cg;
        sred[wid][2] = cb;
        sred[wid][3] = depth;
        sred[wid][4] = 1.0f / fmaxf(1e-10f, depth / acc);
        sred[wid][5] = acc;
    }
    __syncthreads();

    // ---- coalesced epilogue: one multi-lane store per output segment ----
    // out layout (flat, f32): rgb[R,3] | weights[R,128] | depth[R] | disp[R] | acc[R]
    const int t = threadIdx.x;
    if (t < 12) {                       // rgb: 12 consecutive floats per block
        out[(size_t)blockIdx.x * 12 + t] = sred[t / 3][t % 3];
    } else if (t < 16) {                // depth: 4 consecutive floats
        out[131 * R + (size_t)blockIdx.x * 4 + (t - 12)] = sred[t - 12][3];
    } else if (t < 20) {                // disp
        out[132 * R + (size_t)blockIdx.x * 4 + (t - 16)] = sred[t - 16][4];
    } else if (t < 24) {                // acc
        out[133 * R + (size_t)blockIdx.x * 4 + (t - 20)] = sred[t - 20][5];
    }
}

extern "C" void kernel_launch(void* const* d_in, const int* in_sizes, int n_in,
                              void* d_out, int out_size, void* d_ws, size_t ws_size,
                              hipStream_t stream) {
    const float* sigma  = (const float*)d_in[0];
    const float* colors = (const float*)d_in[1];
    const float* z_vals = (const float*)d_in[2];
    const float* rays_d = (const float*)d_in[3];
    float* out = (float*)d_out;

    dim3 block(256);                 // 4 waves = 4 rays per block
    dim3 grid(N_RAYS / 4);           // 65536 blocks
    volrend_kernel<<<grid, block, 0, stream>>>(sigma, colors, z_vals, rays_d, out);
}